// Round 15
// baseline (38.761 us; speedup 1.0000x reference)
//
#include <hip/hip_runtime.h>
#include <hip/hip_bf16.h>

#define B_ 4
#define C_ 64
#define H_ 128
#define W_ 128
#define HW_ (H_ * W_)
#define OCH_ 18

typedef __attribute__((ext_vector_type(2)))  _Float16 half2v;
typedef __attribute__((ext_vector_type(8)))  _Float16 half8;
typedef __attribute__((ext_vector_type(16))) float    f32x16;

// ws layout (elements of unsigned short, FP16 bits):
//   [0, W2B_ELEMS)              w2b: main weights, A-frag order (f16)
//   [W2B_ELEMS, +W2A_ELEMS)     w2a: offset-conv weights, A-frag order (f16)
#define W2B_ELEMS (9 * 2 * 4 * 64 * 8)   // 36864
#define W2A_ELEMS (36 * 64 * 8)          // 18432

// LDS: window 8 planes(8ch) x 5 rows x 128 cols x 16B, NO pad (SWU handles banks).
// 81920 B exactly -> two blocks fit in the 160 KiB pool (2x81920 = 163840).
#define PSTRIDE_B (5 * 128 * 16)         // 10240
#define WIN_BYTES (8 * PSTRIDE_B)        // 81920
#define SMEM_BYTES WIN_BYTES

__device__ __forceinline__ unsigned short f2h(float f) {
  _Float16 h = (_Float16)f;
  return *reinterpret_cast<unsigned short*>(&h);
}
__device__ __forceinline__ half2v pkrtz(float a, float b) {  // cvt_pkrtz, bit-cast
  auto p = __builtin_amdgcn_cvt_pkrtz(a, b);
  return *reinterpret_cast<half2v*>(&p);
}
// bijective XCD swizzle for 512-block grid
__device__ __forceinline__ int swz512(int x) { return (x & 7) * 64 + (x >> 3); }
// Bank-swizzled byte offset of element (row,col) within a plane (16B elements).
__device__ __forceinline__ int SWU(int row, int col) {
  return (((row << 7) + (col & ~3) + ((col & 3) ^ ((col >> 3) & 3))) << 4);
}

// ---------------- weight pack (f16) ----------------
__global__ __launch_bounds__(256) void pack_w_only(
    const float* __restrict__ wmain, const float* __restrict__ offw,
    unsigned short* __restrict__ ws_u) {
  int idx = blockIdx.x * 256 + threadIdx.x;
  if (idx < W2B_ELEMS) {
    int i = idx & 7, lane = (idx >> 3) & 63, s = (idx >> 9) & 3;
    int mq = (idx >> 11) & 1, t = idx >> 12;
    int o = mq * 32 + (lane & 31);
    int c = 16 * s + (lane >> 5) * 8 + i;
    ws_u[idx] = f2h(wmain[(o * 64 + c) * 9 + t]);
  } else if (idx < W2B_ELEMS + W2A_ELEMS) {
    int j = idx - W2B_ELEMS;
    int i = j & 7, lane = (j >> 3) & 63, s = j >> 9;   // s 0..35
    int kg = 16 * s + (lane >> 5) * 8 + i;
    int t = kg >> 6, c = kg & 63, oc = lane & 31;
    ws_u[idx] = (oc < OCH_) ? f2h(offw[(oc * 64 + c) * 9 + t]) : (unsigned short)0;
  }
}

// ---------------- per-tap body (template T): window fast path or global slow path ------
template<int T>
__device__ __forceinline__ void tap_full(
    float dy, float dx, int ho, int px, int lane, int laneh,
    const char* __restrict__ smem, const float* __restrict__ xb,
    const unsigned short* __restrict__ w2b,
    f32x16& acc0, f32x16& acc1) {
  constexpr int KI = T / 3, KJ = T - 3 * (T / 3);
  const float ys = (float)(ho - 1 + KI) + dy;
  const float xs = (float)(px - 1 + KJ) + dx;
  const float y0f = floorf(ys), x0f = floorf(xs);
  const int y0 = (int)y0f, x0 = (int)x0f;
  const int y1 = y0 + 1, x1 = x0 + 1;
  const float wy1 = ys - y0f, wx1 = xs - x0f;
  const float wy0 = 1.f - wy1, wx0 = 1.f - wx1;
  const bool vy0 = (unsigned)y0 < (unsigned)H_, vy1 = (unsigned)y1 < (unsigned)H_;
  const bool vx0 = (unsigned)x0 < (unsigned)W_, vx1 = (unsigned)x1 < (unsigned)W_;
  const float g00 = (vy0 && vx0) ? wy0 * wx0 : 0.f;
  const float g01 = (vy0 && vx1) ? wy0 * wx1 : 0.f;
  const float g10 = (vy1 && vx0) ? wy1 * wx0 : 0.f;
  const float g11 = (vy1 && vx1) ? wy1 * wx1 : 0.f;
  const int yc0 = min(max(y0, 0), H_ - 1), yc1 = min(max(y1, 0), H_ - 1);
  const int xc0 = min(max(x0, 0), W_ - 1), xc1 = min(max(x1, 0), W_ - 1);
  const int rr0 = yc0 - ho + 2, rr1 = yc1 - ho + 2;
  const bool in = ((unsigned)rr0 < 5u) & ((unsigned)rr1 < 5u);
  const unsigned short* wt2 = w2b + T * 4096;

  if (__builtin_expect(__any(!in), 0)) {
    // slow path (|dy| >= ~1): gather from CHW x directly; correct for any offset
    #pragma unroll 1
    for (int ss = 0; ss < 4; ++ss) {
      union { half8 v; _Float16 e[8]; } bf;
      #pragma unroll
      for (int i = 0; i < 8; ++i) {
        const float* img = xb + (size_t)((2 * ss + laneh) * 8 + i) * HW_;
        float v = g00 * img[yc0 * W_ + xc0] + g01 * img[yc0 * W_ + xc1]
                + g10 * img[yc1 * W_ + xc0] + g11 * img[yc1 * W_ + xc1];
        bf.e[i] = (_Float16)v;
      }
      const half8 a0 = *(const half8*)&wt2[(ss * 64 + lane) * 8];
      const half8 a1 = *(const half8*)&wt2[((4 + ss) * 64 + lane) * 8];
      acc0 = __builtin_amdgcn_mfma_f32_32x32x16_f16(a0, bf.v, acc0, 0, 0, 0);
      acc1 = __builtin_amdgcn_mfma_f32_32x32x16_f16(a1, bf.v, acc1, 0, 0, 0);
    }
    return;
  }

  const int cr0 = min(max(rr0, 0), 4), cr1 = min(max(rr1, 0), 4);
  const int u00 = SWU(cr0, xc0), u01 = SWU(cr0, xc1);
  const int u10 = SWU(cr1, xc0), u11 = SWU(cr1, xc1);
  half2v G00; G00.x = G00.y = (_Float16)g00;
  half2v G01; G01.x = G01.y = (_Float16)g01;
  half2v G10; G10.x = G10.y = (_Float16)g10;
  half2v G11; G11.x = G11.y = (_Float16)g11;

  // hoist all 16 corner b128 reads
  half8 c00[4], c01[4], c10[4], c11[4];
  #pragma unroll
  for (int ss = 0; ss < 4; ++ss) {
    const char* pb = smem + (2 * ss + laneh) * PSTRIDE_B;
    c00[ss] = *(const half8*)(pb + u00);
    c01[ss] = *(const half8*)(pb + u01);
    c10[ss] = *(const half8*)(pb + u10);
    c11[ss] = *(const half8*)(pb + u11);
  }
  #pragma unroll
  for (int ss = 0; ss < 4; ++ss) {
    const half2v* p00 = (const half2v*)&c00[ss];
    const half2v* p01 = (const half2v*)&c01[ss];
    const half2v* p10 = (const half2v*)&c10[ss];
    const half2v* p11 = (const half2v*)&c11[ss];
    union { half8 v; half2v h[4]; } bf;
    #pragma unroll
    for (int d = 0; d < 4; ++d)
      bf.h[d] = p00[d] * G00 + p01[d] * G01 + p10[d] * G10 + p11[d] * G11;
    const half8 a0 = *(const half8*)&wt2[(ss * 64 + lane) * 8];
    const half8 a1 = *(const half8*)&wt2[((4 + ss) * 64 + lane) * 8];
    acc0 = __builtin_amdgcn_mfma_f32_32x32x16_f16(a0, bf.v, acc0, 0, 0, 0);
    acc1 = __builtin_amdgcn_mfma_f32_32x32x16_f16(a1, bf.v, acc1, 0, 0, 0);
  }
}

// extract dy/dx for tap T from pacc (C/D: row=oc=(reg&3)+8*(reg>>2)+4*laneh, col=px)
#define EXT(T, DY, DX)                                                                  \
  {                                                                                     \
    constexpr int ocy = 2 * (T), ocx = 2 * (T) + 1;                                     \
    constexpr int ry = (ocy & 3) + 4 * (ocy >> 3), hy = (ocy >> 2) & 1;                 \
    constexpr int rx = (ocx & 3) + 4 * (ocx >> 3), hx = (ocx >> 2) & 1;                 \
    DY = __shfl(pacc[ry], (lane & 31) + (hy << 5)) + ob[ocy];                           \
    DX = __shfl(pacc[rx], (lane & 31) + (hx << 5)) + ob[ocx];                           \
  }

// ---------------- fused kernel v10: 1-row window (80 KB), 2 blocks/CU, tap-split -------
// block=(b, ho): 512 blocks x 512 threads (8 waves = 4 px-strips x 2 tap-groups).
// sub0: taps 0-3, sub1: taps 4-8; P1 duplicated per sub (offsets stay wave-local).
__global__ __launch_bounds__(512, 4) void deform_fused10(
    const float* __restrict__ x, const float* __restrict__ bias,
    const float* __restrict__ ob, const unsigned short* __restrict__ w2b,
    const unsigned short* __restrict__ w2a, float* __restrict__ out) {
  const int blk = swz512(blockIdx.x);
  const int ho = blk & (H_ - 1);
  const int b  = blk >> 7;
  const int tid = threadIdx.x;
  const int lane = tid & 63;
  const int wave = tid >> 6;
  const int pair = wave & 3;
  const int sub  = wave >> 2;
  const int pxl = lane & 31;
  const int px = pair * 32 + pxl;
  const int laneh = lane >> 5;

  __shared__ __align__(16) char smem[SMEM_BYTES];   // 80 KB exactly

  // ---- stage: rows ho-2..ho+2 (clamped), reg transpose, swizzled b128 writes ----
  const float* xb = x + (size_t)b * C_ * HW_;
  #pragma unroll
  for (int it = 0; it < 3; ++it) {
    const int u = tid + it * 512;          // 1280 units: [row(5)][p(8)][col4(32)]
    if (u < 1280) {
      const int row  = u >> 8;
      const int p    = (u >> 5) & 7;
      const int col4 = u & 31;
      const int srow = min(H_ - 1, max(0, ho - 2 + row));
      const float* bp = xb + (size_t)(p * 8) * HW_ + srow * W_ + col4 * 4;
      float4 f[8];
      #pragma unroll
      for (int i = 0; i < 8; ++i) f[i] = *(const float4*)(bp + (size_t)i * HW_);
      char* outb = smem + p * PSTRIDE_B;
      #pragma unroll
      for (int j = 0; j < 4; ++j) {
        union { half8 v; half2v h[4]; } o;
        #pragma unroll
        for (int k = 0; k < 4; ++k)
          o.h[k] = pkrtz(reinterpret_cast<const float*>(&f[2 * k])[j],
                         reinterpret_cast<const float*>(&f[2 * k + 1])[j]);
        *(half8*)(outb + SWU(row, col4 * 4 + j)) = o.v;
      }
    }
  }
  __syncthreads();

  // ---- phase 1: offset conv, full K (duplicated across subs), dual acc chains ----
  f32x16 pacc_a, pacc_b;
  #pragma unroll
  for (int r = 0; r < 16; ++r) { pacc_a[r] = 0.f; pacc_b[r] = 0.f; }

  #pragma unroll 1
  for (int sq = 0; sq < 18; ++sq) {
    #pragma unroll
    for (int h = 0; h < 2; ++h) {
      const int s = 2 * sq + h;
      const int t = s >> 2;
      const int ki = (t >= 6) ? 2 : ((t >= 3) ? 1 : 0);
      const int kj = t - 3 * ki;
      const int row = ho - 1 + ki;
      const int col = px - 1 + kj;
      half8 bfr = {0, 0, 0, 0, 0, 0, 0, 0};
      if (((unsigned)row < (unsigned)H_) && ((unsigned)col < (unsigned)W_))
        bfr = *(const half8*)(smem + ((s & 3) * 2 + laneh) * PSTRIDE_B
                              + SWU(ki + 1, col));
      const half8 afr = *(const half8*)&w2a[((size_t)s * 64 + lane) * 8];
      if (h)
        pacc_b = __builtin_amdgcn_mfma_f32_32x32x16_f16(afr, bfr, pacc_b, 0, 0, 0);
      else
        pacc_a = __builtin_amdgcn_mfma_f32_32x32x16_f16(afr, bfr, pacc_a, 0, 0, 0);
    }
  }
  f32x16 pacc;
  #pragma unroll
  for (int r = 0; r < 16; ++r) pacc[r] = pacc_a[r] + pacc_b[r];

  // ---- phase 2: tap-split (sub0: 0-3, sub1: 4-8); offsets wave-local via shfl ----
  f32x16 acc0, acc1;
  #pragma unroll
  for (int r = 0; r < 16; ++r) { acc0[r] = 0.f; acc1[r] = 0.f; }

  if (sub == 0) {
    float d0y, d0x, d1y, d1x, d2y, d2x, d3y, d3x;
    EXT(0, d0y, d0x); EXT(1, d1y, d1x); EXT(2, d2y, d2x); EXT(3, d3y, d3x);
    tap_full<0>(d0y, d0x, ho, px, lane, laneh, smem, xb, w2b, acc0, acc1);
    tap_full<1>(d1y, d1x, ho, px, lane, laneh, smem, xb, w2b, acc0, acc1);
    tap_full<2>(d2y, d2x, ho, px, lane, laneh, smem, xb, w2b, acc0, acc1);
    tap_full<3>(d3y, d3x, ho, px, lane, laneh, smem, xb, w2b, acc0, acc1);
  } else {
    float d4y, d4x, d5y, d5x, d6y, d6x, d7y, d7x, d8y, d8x;
    EXT(4, d4y, d4x); EXT(5, d5y, d5x); EXT(6, d6y, d6x);
    EXT(7, d7y, d7x); EXT(8, d8y, d8x);
    tap_full<4>(d4y, d4x, ho, px, lane, laneh, smem, xb, w2b, acc0, acc1);
    tap_full<5>(d5y, d5x, ho, px, lane, laneh, smem, xb, w2b, acc0, acc1);
    tap_full<6>(d6y, d6x, ho, px, lane, laneh, smem, xb, w2b, acc0, acc1);
    tap_full<7>(d7y, d7x, ho, px, lane, laneh, smem, xb, w2b, acc0, acc1);
    tap_full<8>(d8y, d8x, ho, px, lane, laneh, smem, xb, w2b, acc0, acc1);
  }

  // ---- reduction across subs via reused window LDS (32 KB region) ----
  __syncthreads();                        // window reads complete
  float* red = (float*)smem;
  if (sub) {
    #pragma unroll
    for (int i = 0; i < 16; ++i) {
      red[(i * 4 + pair) * 64 + lane]        = acc0[i];
      red[((16 + i) * 4 + pair) * 64 + lane] = acc1[i];
    }
  }
  __syncthreads();
  if (!sub) {
    #pragma unroll
    for (int i = 0; i < 16; ++i) {
      acc0[i] += red[(i * 4 + pair) * 64 + lane];
      acc1[i] += red[((16 + i) * 4 + pair) * 64 + lane];
    }
    #pragma unroll
    for (int reg = 0; reg < 16; ++reg) {
      const int row = (reg & 3) + 8 * (reg >> 2) + 4 * laneh;
      out[((b * 64 + row)      * H_ + ho) * W_ + px] = acc0[reg] + bias[row];
      out[((b * 64 + 32 + row) * H_ + ho) * W_ + px] = acc1[reg] + bias[32 + row];
    }
  }
}

extern "C" void kernel_launch(void* const* d_in, const int* in_sizes, int n_in,
                              void* d_out, int out_size, void* d_ws, size_t ws_size,
                              hipStream_t stream) {
  const float* x    = (const float*)d_in[0];
  const float* wt   = (const float*)d_in[1];
  const float* bias = (const float*)d_in[2];
  const float* ow   = (const float*)d_in[3];
  const float* ob   = (const float*)d_in[4];
  float* out = (float*)d_out;

  unsigned short* ws_u = (unsigned short*)d_ws;
  unsigned short* w2b  = ws_u;
  unsigned short* w2a  = ws_u + W2B_ELEMS;

  const int pack_blocks = (W2B_ELEMS + W2A_ELEMS + 255) / 256;   // 216
  pack_w_only<<<pack_blocks, 256, 0, stream>>>(wt, ow, ws_u);

  deform_fused10<<<B_ * H_, 512, 0, stream>>>(x, bias, ob, w2b, w2a, out);
}

// Round 17
// 37.023 us; speedup vs baseline: 1.0470x; 1.0470x over previous
//
#include <hip/hip_runtime.h>
#include <hip/hip_bf16.h>

#define B_ 4
#define C_ 64
#define H_ 128
#define W_ 128
#define HW_ (H_ * W_)
#define OCH_ 18

typedef __attribute__((ext_vector_type(2)))  _Float16 half2v;
typedef __attribute__((ext_vector_type(8)))  _Float16 half8;
typedef __attribute__((ext_vector_type(16))) float    f32x16;

// ws layout (elements of unsigned short, FP16 bits):
//   [0, W2B_ELEMS)              w2b: main weights, A-frag order (f16)
//   [W2B_ELEMS, +W2A_ELEMS)     w2a: offset-conv weights, A-frag order (f16)
#define W2B_ELEMS (9 * 2 * 4 * 64 * 8)   // 36864
#define W2A_ELEMS (36 * 64 * 8)          // 18432

// LDS: window 8 planes(8ch) x 6 rows x 128 cols x 16B (+pad), then per-wave offset
// exchange region: 8 waves x 18 oc x 32 px floats.
#define PSTRIDE_B (6 * 128 * 16 + 16)    // 12304
#define WIN_BYTES (8 * PSTRIDE_B)        // 98432
#define OFFL_OFS  WIN_BYTES
#define OFFW_B    (OCH_ * 32 * 4)        // 2304 per wave
#define SMEM_BYTES (WIN_BYTES + 8 * OFFW_B)   // 116864

__device__ __forceinline__ unsigned short f2h(float f) {   // f32 -> f16 bits (RNE)
  _Float16 h = (_Float16)f;
  return *reinterpret_cast<unsigned short*>(&h);
}
__device__ __forceinline__ half2v pkrtz(float a, float b) {  // cvt_pkrtz, bit-cast
  auto p = __builtin_amdgcn_cvt_pkrtz(a, b);
  return *reinterpret_cast<half2v*>(&p);
}
// bijective XCD swizzle for 256-block grid; consecutive ho0 stay on one XCD
__device__ __forceinline__ int swz256(int x) { return (x & 7) * 32 + (x >> 3); }
// Bank-swizzled byte offset of element (row,col) in a window plane (16B elems).
__device__ __forceinline__ int SWU(int row, int col) {
  return (((row << 7) + (col & ~3) + ((col & 3) ^ ((col >> 3) & 3))) << 4);
}

// ---------------- weight pack (f16) ----------------
__global__ __launch_bounds__(256) void pack_w_only(
    const float* __restrict__ wmain, const float* __restrict__ offw,
    unsigned short* __restrict__ ws_u) {
  int idx = blockIdx.x * 256 + threadIdx.x;
  if (idx < W2B_ELEMS) {
    int i = idx & 7, lane = (idx >> 3) & 63, s = (idx >> 9) & 3;
    int mq = (idx >> 11) & 1, t = idx >> 12;
    int o = mq * 32 + (lane & 31);
    int c = 16 * s + (lane >> 5) * 8 + i;
    ws_u[idx] = f2h(wmain[(o * 64 + c) * 9 + t]);
  } else if (idx < W2B_ELEMS + W2A_ELEMS) {
    int j = idx - W2B_ELEMS;
    int i = j & 7, lane = (j >> 3) & 63, s = j >> 9;   // s 0..35
    int kg = 16 * s + (lane >> 5) * 8 + i;
    int t = kg >> 6, c = kg & 63, oc = lane & 31;
    ws_u[idx] = (oc < OCH_) ? f2h(offw[(oc * 64 + c) * 9 + t]) : (unsigned short)0;
  }
}

// ---------------- branchless fast tap (template T) ----------------
template<int T>
__device__ __forceinline__ void tap_fast(
    const float* __restrict__ offl, int pxl, int ho, int ho0, int px,
    int lane, int laneh, const char* __restrict__ smem,
    const unsigned short* __restrict__ w2b,
    f32x16& acc0, f32x16& acc1, unsigned& fm) {
  constexpr int KI = T / 3, KJ = T - 3 * (T / 3);
  const float dy = offl[(2 * T) * 32 + pxl];
  const float dx = offl[(2 * T + 1) * 32 + pxl];
  const float ys = (float)(ho - 1 + KI) + dy;
  const float xs = (float)(px - 1 + KJ) + dx;
  const float y0f = floorf(ys), x0f = floorf(xs);
  const int y0 = (int)y0f, x0 = (int)x0f;
  const int y1 = y0 + 1, x1 = x0 + 1;
  const float wy1 = ys - y0f, wx1 = xs - x0f;
  const float wy0 = 1.f - wy1, wx0 = 1.f - wx1;
  const bool vy0 = (unsigned)y0 < (unsigned)H_, vy1 = (unsigned)y1 < (unsigned)H_;
  const bool vx0 = (unsigned)x0 < (unsigned)W_, vx1 = (unsigned)x1 < (unsigned)W_;
  const float g00 = (vy0 && vx0) ? wy0 * wx0 : 0.f;
  const float g01 = (vy0 && vx1) ? wy0 * wx1 : 0.f;
  const float g10 = (vy1 && vx0) ? wy1 * wx0 : 0.f;
  const float g11 = (vy1 && vx1) ? wy1 * wx1 : 0.f;
  const int yc0 = min(max(y0, 0), H_ - 1), yc1 = min(max(y1, 0), H_ - 1);
  const int xc0 = min(max(x0, 0), W_ - 1), xc1 = min(max(x1, 0), W_ - 1);
  const int rr0 = yc0 - ho0 + 2, rr1 = yc1 - ho0 + 2;
  const bool wr0 = (unsigned)rr0 < 6u, wr1 = (unsigned)rr1 < 6u;
  // zero the weights of out-of-window corners (per-lane); fixup adds them later
  const float gg00 = wr0 ? g00 : 0.f, gg01 = wr0 ? g01 : 0.f;
  const float gg10 = wr1 ? g10 : 0.f, gg11 = wr1 ? g11 : 0.f;
  if (__any((!wr0 & (vy0 & (vx0 | vx1))) | (!wr1 & (vy1 & (vx0 | vx1)))))
    fm |= (1u << T);
  const int cr0 = min(max(rr0, 0), 5), cr1 = min(max(rr1, 0), 5);
  const int u00 = SWU(cr0, xc0), u01 = SWU(cr0, xc1);
  const int u10 = SWU(cr1, xc0), u11 = SWU(cr1, xc1);
  half2v G00; G00.x = G00.y = (_Float16)gg00;
  half2v G01; G01.x = G01.y = (_Float16)gg01;
  half2v G10; G10.x = G10.y = (_Float16)gg10;
  half2v G11; G11.x = G11.y = (_Float16)gg11;
  const unsigned short* wt2 = w2b + T * 4096;

  __builtin_amdgcn_s_setprio(1);
  #pragma unroll
  for (int ss = 0; ss < 4; ++ss) {
    const char* pb = smem + (2 * ss + laneh) * PSTRIDE_B;
    const half8 c00 = *(const half8*)(pb + u00);
    const half8 c01 = *(const half8*)(pb + u01);
    const half8 c10 = *(const half8*)(pb + u10);
    const half8 c11 = *(const half8*)(pb + u11);
    const half2v* p00 = (const half2v*)&c00;
    const half2v* p01 = (const half2v*)&c01;
    const half2v* p10 = (const half2v*)&c10;
    const half2v* p11 = (const half2v*)&c11;
    union { half8 v; half2v h[4]; } bf;
    #pragma unroll
    for (int d = 0; d < 4; ++d)    // 4x v_pk ops per dword, no unpack/repack
      bf.h[d] = p00[d] * G00 + p01[d] * G01 + p10[d] * G10 + p11[d] * G11;
    const half8 a0 = *(const half8*)&wt2[(ss * 64 + lane) * 8];
    const half8 a1 = *(const half8*)&wt2[((4 + ss) * 64 + lane) * 8];
    acc0 = __builtin_amdgcn_mfma_f32_32x32x16_f16(a0, bf.v, acc0, 0, 0, 0);
    acc1 = __builtin_amdgcn_mfma_f32_32x32x16_f16(a1, bf.v, acc1, 0, 0, 0);
  }
  __builtin_amdgcn_s_setprio(0);
}

// ---------------- fused kernel v12: r14 winner (v9) + setprio only ----------------
// block=(b, ho0=2*rb): 256 blocks x 512 threads (8 waves).
// wave = (r_off = wave>>2, pair = wave&3): output row ho0+r_off, px strip pair*32..+32.
__global__ __launch_bounds__(512, 2) void deform_fused12(
    const float* __restrict__ x, const float* __restrict__ bias,
    const float* __restrict__ ob, const unsigned short* __restrict__ w2b,
    const unsigned short* __restrict__ w2a, float* __restrict__ out) {
  const int blk = swz256(blockIdx.x);
  const int ho0 = (blk & 63) * 2;
  const int b   = blk >> 6;
  const int tid = threadIdx.x;
  const int lane = tid & 63;
  const int wave = tid >> 6;
  const int r_off = wave >> 2;
  const int pair  = wave & 3;
  const int ho = ho0 + r_off;
  const int pxl = lane & 31;
  const int px = pair * 32 + pxl;
  const int laneh = lane >> 5;

  __shared__ __align__(16) char smem[SMEM_BYTES];

  // ---- stage: rows ho0-2..ho0+3 (clamped), reg transpose, swizzled b128 writes ----
  const float* xb = x + (size_t)b * C_ * HW_;
  #pragma unroll
  for (int it = 0; it < 3; ++it) {
    const int u = tid + it * 512;          // 1536 units: [row(6)][p(8)][col4(32)]
    const int row  = u >> 8;
    const int p    = (u >> 5) & 7;
    const int col4 = u & 31;
    const int srow = min(H_ - 1, max(0, ho0 - 2 + row));
    const float* bp = xb + (size_t)(p * 8) * HW_ + srow * W_ + col4 * 4;
    float4 f[8];
    #pragma unroll
    for (int i = 0; i < 8; ++i) f[i] = *(const float4*)(bp + (size_t)i * HW_);
    char* outb = smem + p * PSTRIDE_B;
    #pragma unroll
    for (int j = 0; j < 4; ++j) {
      union { half8 v; half2v h[4]; } o;
      #pragma unroll
      for (int k = 0; k < 4; ++k)
        o.h[k] = pkrtz(reinterpret_cast<const float*>(&f[2 * k])[j],
                       reinterpret_cast<const float*>(&f[2 * k + 1])[j]);
      *(half8*)(outb + SWU(row, col4 * 4 + j)) = o.v;
    }
  }
  __syncthreads();                         // the only barrier

  // ---- phase 1: offset conv, rolled (18 x dual-chain), f16 MFMA ----
  f32x16 pacc_a, pacc_b;
  #pragma unroll
  for (int r = 0; r < 16; ++r) { pacc_a[r] = 0.f; pacc_b[r] = 0.f; }

  #pragma unroll 1
  for (int sq = 0; sq < 18; ++sq) {
    #pragma unroll
    for (int h = 0; h < 2; ++h) {
      const int s = 2 * sq + h;
      const int t = s >> 2;
      const int ki = (t >= 6) ? 2 : ((t >= 3) ? 1 : 0);
      const int kj = t - 3 * ki;
      const int row = ho - 1 + ki;
      const int col = px - 1 + kj;
      half8 bfr = {0, 0, 0, 0, 0, 0, 0, 0};
      if (((unsigned)row < (unsigned)H_) && ((unsigned)col < (unsigned)W_))
        bfr = *(const half8*)(smem + ((s & 3) * 2 + laneh) * PSTRIDE_B
                              + SWU(ki + 1 + r_off, col));
      const half8 afr = *(const half8*)&w2a[((size_t)s * 64 + lane) * 8];
      if (h)
        pacc_b = __builtin_amdgcn_mfma_f32_32x32x16_f16(afr, bfr, pacc_b, 0, 0, 0);
      else
        pacc_a = __builtin_amdgcn_mfma_f32_32x32x16_f16(afr, bfr, pacc_a, 0, 0, 0);
    }
  }

  // ---- write offsets (+bias) to wave-private LDS region; no barrier needed ----
  float* offl = (float*)(smem + OFFL_OFS + wave * OFFW_B);
  #pragma unroll
  for (int reg = 0; reg < 16; ++reg) {
    const int oc = (reg & 3) + 8 * (reg >> 2) + 4 * laneh;
    if (oc < OCH_) offl[oc * 32 + pxl] = pacc_a[reg] + pacc_b[reg] + ob[oc];
  }

  // ---- phase 2: 9 branchless taps (unrolled, free to pipeline) ----
  f32x16 acc0, acc1;
  #pragma unroll
  for (int r = 0; r < 16; ++r) { acc0[r] = 0.f; acc1[r] = 0.f; }
  unsigned fm = 0;

  tap_fast<0>(offl, pxl, ho, ho0, px, lane, laneh, smem, w2b, acc0, acc1, fm);
  tap_fast<1>(offl, pxl, ho, ho0, px, lane, laneh, smem, w2b, acc0, acc1, fm);
  tap_fast<2>(offl, pxl, ho, ho0, px, lane, laneh, smem, w2b, acc0, acc1, fm);
  tap_fast<3>(offl, pxl, ho, ho0, px, lane, laneh, smem, w2b, acc0, acc1, fm);
  tap_fast<4>(offl, pxl, ho, ho0, px, lane, laneh, smem, w2b, acc0, acc1, fm);
  tap_fast<5>(offl, pxl, ho, ho0, px, lane, laneh, smem, w2b, acc0, acc1, fm);
  tap_fast<6>(offl, pxl, ho, ho0, px, lane, laneh, smem, w2b, acc0, acc1, fm);
  tap_fast<7>(offl, pxl, ho, ho0, px, lane, laneh, smem, w2b, acc0, acc1, fm);
  tap_fast<8>(offl, pxl, ho, ho0, px, lane, laneh, smem, w2b, acc0, acc1, fm);

  // ---- rare fixup: add contributions of out-of-window corners from global ----
  if (__builtin_expect(fm != 0, 0)) {
    #pragma unroll 1
    for (int t = 0; t < 9; ++t) {
      if (!((fm >> t) & 1)) continue;
      const int ki = (t >= 6) ? 2 : ((t >= 3) ? 1 : 0);
      const int kj = t - 3 * ki;
      const float dy = offl[(2 * t) * 32 + pxl];
      const float dx = offl[(2 * t + 1) * 32 + pxl];
      const float ys = (float)(ho - 1 + ki) + dy;
      const float xs = (float)(px - 1 + kj) + dx;
      const float y0f = floorf(ys), x0f = floorf(xs);
      const int y0 = (int)y0f, x0 = (int)x0f;
      const int y1 = y0 + 1, x1 = x0 + 1;
      const float wy1 = ys - y0f, wx1 = xs - x0f;
      const float wy0 = 1.f - wy1, wx0 = 1.f - wx1;
      const bool vy0 = (unsigned)y0 < (unsigned)H_, vy1 = (unsigned)y1 < (unsigned)H_;
      const bool vx0 = (unsigned)x0 < (unsigned)W_, vx1 = (unsigned)x1 < (unsigned)W_;
      float g00 = (vy0 && vx0) ? wy0 * wx0 : 0.f;
      float g01 = (vy0 && vx1) ? wy0 * wx1 : 0.f;
      float g10 = (vy1 && vx0) ? wy1 * wx0 : 0.f;
      float g11 = (vy1 && vx1) ? wy1 * wx1 : 0.f;
      const int yc0 = min(max(y0, 0), H_ - 1), yc1 = min(max(y1, 0), H_ - 1);
      const int xc0 = min(max(x0, 0), W_ - 1), xc1 = min(max(x1, 0), W_ - 1);
      const bool wr0 = (unsigned)(yc0 - ho0 + 2) < 6u;
      const bool wr1 = (unsigned)(yc1 - ho0 + 2) < 6u;
      // only the corners that were zeroed in the fast path
      g00 = wr0 ? 0.f : g00; g01 = wr0 ? 0.f : g01;
      g10 = wr1 ? 0.f : g10; g11 = wr1 ? 0.f : g11;
      const unsigned short* wt2 = w2b + t * 4096;
      #pragma unroll 1
      for (int ss = 0; ss < 4; ++ss) {
        union { half8 v; _Float16 e[8]; } bf;
        #pragma unroll
        for (int i = 0; i < 8; ++i) {
          const float* img = xb + (size_t)((2 * ss + laneh) * 8 + i) * HW_;
          float v = g00 * img[yc0 * W_ + xc0] + g01 * img[yc0 * W_ + xc1]
                  + g10 * img[yc1 * W_ + xc0] + g11 * img[yc1 * W_ + xc1];
          bf.e[i] = (_Float16)v;
        }
        const half8 a0 = *(const half8*)&wt2[(ss * 64 + lane) * 8];
        const half8 a1 = *(const half8*)&wt2[((4 + ss) * 64 + lane) * 8];
        acc0 = __builtin_amdgcn_mfma_f32_32x32x16_f16(a0, bf.v, acc0, 0, 0, 0);
        acc1 = __builtin_amdgcn_mfma_f32_32x32x16_f16(a1, bf.v, acc1, 0, 0, 0);
      }
    }
  }

  // ---- epilogue: direct stores (wave owns full M=64 of its strip) ----
  #pragma unroll
  for (int reg = 0; reg < 16; ++reg) {
    const int row = (reg & 3) + 8 * (reg >> 2) + 4 * laneh;
    out[((b * 64 + row)      * H_ + ho) * W_ + px] = acc0[reg] + bias[row];
    out[((b * 64 + 32 + row) * H_ + ho) * W_ + px] = acc1[reg] + bias[32 + row];
  }
}

extern "C" void kernel_launch(void* const* d_in, const int* in_sizes, int n_in,
                              void* d_out, int out_size, void* d_ws, size_t ws_size,
                              hipStream_t stream) {
  const float* x    = (const float*)d_in[0];
  const float* wt   = (const float*)d_in[1];
  const float* bias = (const float*)d_in[2];
  const float* ow   = (const float*)d_in[3];
  const float* ob   = (const float*)d_in[4];
  float* out = (float*)d_out;

  unsigned short* ws_u = (unsigned short*)d_ws;
  unsigned short* w2b  = ws_u;
  unsigned short* w2a  = ws_u + W2B_ELEMS;

  const int pack_blocks = (W2B_ELEMS + W2A_ELEMS + 255) / 256;   // 216
  pack_w_only<<<pack_blocks, 256, 0, stream>>>(wt, ow, ws_u);

  deform_fused12<<<B_ * (H_ / 2), 512, 0, stream>>>(x, bias, ob, w2b, w2a, out);
}

// Round 18
// 36.590 us; speedup vs baseline: 1.0593x; 1.0118x over previous
//
#include <hip/hip_runtime.h>
#include <hip/hip_bf16.h>

#define B_ 4
#define C_ 64
#define H_ 128
#define W_ 128
#define HW_ (H_ * W_)
#define OCH_ 18

typedef __attribute__((ext_vector_type(2)))  _Float16 half2v;
typedef __attribute__((ext_vector_type(8)))  _Float16 half8;
typedef __attribute__((ext_vector_type(16))) float    f32x16;

// ws layout (elements of unsigned short, FP16 bits):
//   [0, W2B_ELEMS)              w2b: main weights, A-frag order (f16)
//   [W2B_ELEMS, +W2A_ELEMS)     w2a: offset-conv weights, A-frag order (f16)
#define W2B_ELEMS (9 * 2 * 4 * 64 * 8)   // 36864
#define W2A_ELEMS (36 * 64 * 8)          // 18432

// LDS: window 8 planes(8ch) x 6 rows x 128 cols x 16B (+pad), then per-wave offset
// exchange region (fixup path only): 8 waves x 18 oc x 32 px floats.
#define PSTRIDE_B (6 * 128 * 16 + 16)    // 12304
#define WIN_BYTES (8 * PSTRIDE_B)        // 98432
#define OFFL_OFS  WIN_BYTES
#define OFFW_B    (OCH_ * 32 * 4)        // 2304 per wave
#define SMEM_BYTES (WIN_BYTES + 8 * OFFW_B)   // 116864

__device__ __forceinline__ unsigned short f2h(float f) {   // f32 -> f16 bits (RNE)
  _Float16 h = (_Float16)f;
  return *reinterpret_cast<unsigned short*>(&h);
}
__device__ __forceinline__ half2v pkrtz(float a, float b) {  // cvt_pkrtz, bit-cast
  auto p = __builtin_amdgcn_cvt_pkrtz(a, b);
  return *reinterpret_cast<half2v*>(&p);
}
// bijective XCD swizzle for 256-block grid; consecutive ho0 stay on one XCD
__device__ __forceinline__ int swz256(int x) { return (x & 7) * 32 + (x >> 3); }
// Bank-swizzled byte offset of element (row,col) in a window plane (16B elems).
__device__ __forceinline__ int SWU(int row, int col) {
  return (((row << 7) + (col & ~3) + ((col & 3) ^ ((col >> 3) & 3))) << 4);
}

// ---------------- weight pack (f16) ----------------
__global__ __launch_bounds__(256) void pack_w_only(
    const float* __restrict__ wmain, const float* __restrict__ offw,
    unsigned short* __restrict__ ws_u) {
  int idx = blockIdx.x * 256 + threadIdx.x;
  if (idx < W2B_ELEMS) {
    int i = idx & 7, lane = (idx >> 3) & 63, s = (idx >> 9) & 3;
    int mq = (idx >> 11) & 1, t = idx >> 12;
    int o = mq * 32 + (lane & 31);
    int c = 16 * s + (lane >> 5) * 8 + i;
    ws_u[idx] = f2h(wmain[(o * 64 + c) * 9 + t]);
  } else if (idx < W2B_ELEMS + W2A_ELEMS) {
    int j = idx - W2B_ELEMS;
    int i = j & 7, lane = (j >> 3) & 63, s = j >> 9;   // s 0..35
    int kg = 16 * s + (lane >> 5) * 8 + i;
    int t = kg >> 6, c = kg & 63, oc = lane & 31;
    ws_u[idx] = (oc < OCH_) ? f2h(offw[(oc * 64 + c) * 9 + t]) : (unsigned short)0;
  }
}

// ---------------- branchless fast tap (template T); dy/dx in registers ----------------
template<int T>
__device__ __forceinline__ void tap_fast(
    float dy, float dx, int ho, int ho0, int px,
    int lane, int laneh, const char* __restrict__ smem,
    const unsigned short* __restrict__ w2b,
    f32x16& acc0, f32x16& acc1, unsigned& fm) {
  constexpr int KI = T / 3, KJ = T - 3 * (T / 3);
  const float ys = (float)(ho - 1 + KI) + dy;
  const float xs = (float)(px - 1 + KJ) + dx;
  const float y0f = floorf(ys), x0f = floorf(xs);
  const int y0 = (int)y0f, x0 = (int)x0f;
  const int y1 = y0 + 1, x1 = x0 + 1;
  const float wy1 = ys - y0f, wx1 = xs - x0f;
  const float wy0 = 1.f - wy1, wx0 = 1.f - wx1;
  const bool vy0 = (unsigned)y0 < (unsigned)H_, vy1 = (unsigned)y1 < (unsigned)H_;
  const bool vx0 = (unsigned)x0 < (unsigned)W_, vx1 = (unsigned)x1 < (unsigned)W_;
  const float g00 = (vy0 && vx0) ? wy0 * wx0 : 0.f;
  const float g01 = (vy0 && vx1) ? wy0 * wx1 : 0.f;
  const float g10 = (vy1 && vx0) ? wy1 * wx0 : 0.f;
  const float g11 = (vy1 && vx1) ? wy1 * wx1 : 0.f;
  const int yc0 = min(max(y0, 0), H_ - 1), yc1 = min(max(y1, 0), H_ - 1);
  const int xc0 = min(max(x0, 0), W_ - 1), xc1 = min(max(x1, 0), W_ - 1);
  const int rr0 = yc0 - ho0 + 2, rr1 = yc1 - ho0 + 2;
  const bool wr0 = (unsigned)rr0 < 6u, wr1 = (unsigned)rr1 < 6u;
  // zero the weights of out-of-window corners (per-lane); fixup adds them later
  const float gg00 = wr0 ? g00 : 0.f, gg01 = wr0 ? g01 : 0.f;
  const float gg10 = wr1 ? g10 : 0.f, gg11 = wr1 ? g11 : 0.f;
  if (__any((!wr0 & (vy0 & (vx0 | vx1))) | (!wr1 & (vy1 & (vx0 | vx1)))))
    fm |= (1u << T);
  const int cr0 = min(max(rr0, 0), 5), cr1 = min(max(rr1, 0), 5);
  const int u00 = SWU(cr0, xc0), u01 = SWU(cr0, xc1);
  const int u10 = SWU(cr1, xc0), u11 = SWU(cr1, xc1);
  half2v G00; G00.x = G00.y = (_Float16)gg00;
  half2v G01; G01.x = G01.y = (_Float16)gg01;
  half2v G10; G10.x = G10.y = (_Float16)gg10;
  half2v G11; G11.x = G11.y = (_Float16)gg11;
  const unsigned short* wt2 = w2b + T * 4096;

  __builtin_amdgcn_s_setprio(1);
  #pragma unroll
  for (int ss = 0; ss < 4; ++ss) {
    const char* pb = smem + (2 * ss + laneh) * PSTRIDE_B;
    const half8 c00 = *(const half8*)(pb + u00);
    const half8 c01 = *(const half8*)(pb + u01);
    const half8 c10 = *(const half8*)(pb + u10);
    const half8 c11 = *(const half8*)(pb + u11);
    const half2v* p00 = (const half2v*)&c00;
    const half2v* p01 = (const half2v*)&c01;
    const half2v* p10 = (const half2v*)&c10;
    const half2v* p11 = (const half2v*)&c11;
    union { half8 v; half2v h[4]; } bf;
    #pragma unroll
    for (int d = 0; d < 4; ++d)    // 4x v_pk ops per dword, no unpack/repack
      bf.h[d] = p00[d] * G00 + p01[d] * G01 + p10[d] * G10 + p11[d] * G11;
    const half8 a0 = *(const half8*)&wt2[(ss * 64 + lane) * 8];
    const half8 a1 = *(const half8*)&wt2[((4 + ss) * 64 + lane) * 8];
    acc0 = __builtin_amdgcn_mfma_f32_32x32x16_f16(a0, bf.v, acc0, 0, 0, 0);
    acc1 = __builtin_amdgcn_mfma_f32_32x32x16_f16(a1, bf.v, acc1, 0, 0, 0);
  }
  __builtin_amdgcn_s_setprio(0);
}

// extract dy/dx for tap T from pacc via shfl (C/D: row=(reg&3)+8*(reg>>2)+4*laneh,
// col=lane&31; oc -> reg=(oc&3)+4*(oc>>3), h=(oc>>2)&1). Proven in r10 kernel.
#define EXT(T, DY, DX)                                                                  \
  {                                                                                     \
    constexpr int ocy = 2 * (T), ocx = 2 * (T) + 1;                                     \
    constexpr int ry = (ocy & 3) + 4 * (ocy >> 3), hy = (ocy >> 2) & 1;                 \
    constexpr int rx = (ocx & 3) + 4 * (ocx >> 3), hx = (ocx >> 2) & 1;                 \
    DY = __shfl(pacc[ry], (lane & 31) + (hy << 5)) + ob[ocy];                           \
    DX = __shfl(pacc[rx], (lane & 31) + (hx << 5)) + ob[ocx];                           \
  }

// ---------------- fused kernel v13: v12 + EXT-shfl register offsets ----------------
// block=(b, ho0=2*rb): 256 blocks x 512 threads (8 waves).
// wave = (r_off = wave>>2, pair = wave&3): output row ho0+r_off, px strip pair*32..+32.
__global__ __launch_bounds__(512, 2) void deform_fused13(
    const float* __restrict__ x, const float* __restrict__ bias,
    const float* __restrict__ ob, const unsigned short* __restrict__ w2b,
    const unsigned short* __restrict__ w2a, float* __restrict__ out) {
  const int blk = swz256(blockIdx.x);
  const int ho0 = (blk & 63) * 2;
  const int b   = blk >> 6;
  const int tid = threadIdx.x;
  const int lane = tid & 63;
  const int wave = tid >> 6;
  const int r_off = wave >> 2;
  const int pair  = wave & 3;
  const int ho = ho0 + r_off;
  const int pxl = lane & 31;
  const int px = pair * 32 + pxl;
  const int laneh = lane >> 5;

  __shared__ __align__(16) char smem[SMEM_BYTES];

  // ---- stage: rows ho0-2..ho0+3 (clamped), reg transpose, swizzled b128 writes ----
  const float* xb = x + (size_t)b * C_ * HW_;
  #pragma unroll
  for (int it = 0; it < 3; ++it) {
    const int u = tid + it * 512;          // 1536 units: [row(6)][p(8)][col4(32)]
    const int row  = u >> 8;
    const int p    = (u >> 5) & 7;
    const int col4 = u & 31;
    const int srow = min(H_ - 1, max(0, ho0 - 2 + row));
    const float* bp = xb + (size_t)(p * 8) * HW_ + srow * W_ + col4 * 4;
    float4 f[8];
    #pragma unroll
    for (int i = 0; i < 8; ++i) f[i] = *(const float4*)(bp + (size_t)i * HW_);
    char* outb = smem + p * PSTRIDE_B;
    #pragma unroll
    for (int j = 0; j < 4; ++j) {
      union { half8 v; half2v h[4]; } o;
      #pragma unroll
      for (int k = 0; k < 4; ++k)
        o.h[k] = pkrtz(reinterpret_cast<const float*>(&f[2 * k])[j],
                       reinterpret_cast<const float*>(&f[2 * k + 1])[j]);
      *(half8*)(outb + SWU(row, col4 * 4 + j)) = o.v;
    }
  }
  __syncthreads();                         // the only barrier

  // ---- phase 1: offset conv, rolled (18 x dual-chain), f16 MFMA ----
  f32x16 pacc_a, pacc_b;
  #pragma unroll
  for (int r = 0; r < 16; ++r) { pacc_a[r] = 0.f; pacc_b[r] = 0.f; }

  #pragma unroll 1
  for (int sq = 0; sq < 18; ++sq) {
    #pragma unroll
    for (int h = 0; h < 2; ++h) {
      const int s = 2 * sq + h;
      const int t = s >> 2;
      const int ki = (t >= 6) ? 2 : ((t >= 3) ? 1 : 0);
      const int kj = t - 3 * ki;
      const int row = ho - 1 + ki;
      const int col = px - 1 + kj;
      half8 bfr = {0, 0, 0, 0, 0, 0, 0, 0};
      if (((unsigned)row < (unsigned)H_) && ((unsigned)col < (unsigned)W_))
        bfr = *(const half8*)(smem + ((s & 3) * 2 + laneh) * PSTRIDE_B
                              + SWU(ki + 1 + r_off, col));
      const half8 afr = *(const half8*)&w2a[((size_t)s * 64 + lane) * 8];
      if (h)
        pacc_b = __builtin_amdgcn_mfma_f32_32x32x16_f16(afr, bfr, pacc_b, 0, 0, 0);
      else
        pacc_a = __builtin_amdgcn_mfma_f32_32x32x16_f16(afr, bfr, pacc_a, 0, 0, 0);
    }
  }

  f32x16 pacc;
  #pragma unroll
  for (int r = 0; r < 16; ++r) pacc[r] = pacc_a[r] + pacc_b[r];

  // ---- write offsets (+bias) to wave-private LDS region (fixup path only) ----
  float* offl = (float*)(smem + OFFL_OFS + wave * OFFW_B);
  #pragma unroll
  for (int reg = 0; reg < 16; ++reg) {
    const int oc = (reg & 3) + 8 * (reg >> 2) + 4 * laneh;
    if (oc < OCH_) offl[oc * 32 + pxl] = pacc[reg] + ob[oc];
  }

  // ---- extract all 9 taps' offsets into registers via shfl (no LDS on fast path) ----
  float d0y, d0x, d1y, d1x, d2y, d2x, d3y, d3x, d4y, d4x;
  float d5y, d5x, d6y, d6x, d7y, d7x, d8y, d8x;
  EXT(0, d0y, d0x); EXT(1, d1y, d1x); EXT(2, d2y, d2x);
  EXT(3, d3y, d3x); EXT(4, d4y, d4x); EXT(5, d5y, d5x);
  EXT(6, d6y, d6x); EXT(7, d7y, d7x); EXT(8, d8y, d8x);

  // ---- phase 2: 9 branchless taps (unrolled, pure register dataflow) ----
  f32x16 acc0, acc1;
  #pragma unroll
  for (int r = 0; r < 16; ++r) { acc0[r] = 0.f; acc1[r] = 0.f; }
  unsigned fm = 0;

  tap_fast<0>(d0y, d0x, ho, ho0, px, lane, laneh, smem, w2b, acc0, acc1, fm);
  tap_fast<1>(d1y, d1x, ho, ho0, px, lane, laneh, smem, w2b, acc0, acc1, fm);
  tap_fast<2>(d2y, d2x, ho, ho0, px, lane, laneh, smem, w2b, acc0, acc1, fm);
  tap_fast<3>(d3y, d3x, ho, ho0, px, lane, laneh, smem, w2b, acc0, acc1, fm);
  tap_fast<4>(d4y, d4x, ho, ho0, px, lane, laneh, smem, w2b, acc0, acc1, fm);
  tap_fast<5>(d5y, d5x, ho, ho0, px, lane, laneh, smem, w2b, acc0, acc1, fm);
  tap_fast<6>(d6y, d6x, ho, ho0, px, lane, laneh, smem, w2b, acc0, acc1, fm);
  tap_fast<7>(d7y, d7x, ho, ho0, px, lane, laneh, smem, w2b, acc0, acc1, fm);
  tap_fast<8>(d8y, d8x, ho, ho0, px, lane, laneh, smem, w2b, acc0, acc1, fm);

  // ---- rare fixup: add contributions of out-of-window corners from global ----
  if (__builtin_expect(fm != 0, 0)) {
    #pragma unroll 1
    for (int t = 0; t < 9; ++t) {
      if (!((fm >> t) & 1)) continue;
      const int ki = (t >= 6) ? 2 : ((t >= 3) ? 1 : 0);
      const int kj = t - 3 * ki;
      const float dy = offl[(2 * t) * 32 + pxl];
      const float dx = offl[(2 * t + 1) * 32 + pxl];
      const float ys = (float)(ho - 1 + ki) + dy;
      const float xs = (float)(px - 1 + kj) + dx;
      const float y0f = floorf(ys), x0f = floorf(xs);
      const int y0 = (int)y0f, x0 = (int)x0f;
      const int y1 = y0 + 1, x1 = x0 + 1;
      const float wy1 = ys - y0f, wx1 = xs - x0f;
      const float wy0 = 1.f - wy1, wx0 = 1.f - wx1;
      const bool vy0 = (unsigned)y0 < (unsigned)H_, vy1 = (unsigned)y1 < (unsigned)H_;
      const bool vx0 = (unsigned)x0 < (unsigned)W_, vx1 = (unsigned)x1 < (unsigned)W_;
      float g00 = (vy0 && vx0) ? wy0 * wx0 : 0.f;
      float g01 = (vy0 && vx1) ? wy0 * wx1 : 0.f;
      float g10 = (vy1 && vx0) ? wy1 * wx0 : 0.f;
      float g11 = (vy1 && vx1) ? wy1 * wx1 : 0.f;
      const int yc0 = min(max(y0, 0), H_ - 1), yc1 = min(max(y1, 0), H_ - 1);
      const int xc0 = min(max(x0, 0), W_ - 1), xc1 = min(max(x1, 0), W_ - 1);
      const bool wr0 = (unsigned)(yc0 - ho0 + 2) < 6u;
      const bool wr1 = (unsigned)(yc1 - ho0 + 2) < 6u;
      // only the corners that were zeroed in the fast path
      g00 = wr0 ? 0.f : g00; g01 = wr0 ? 0.f : g01;
      g10 = wr1 ? 0.f : g10; g11 = wr1 ? 0.f : g11;
      const unsigned short* wt2 = w2b + t * 4096;
      #pragma unroll 1
      for (int ss = 0; ss < 4; ++ss) {
        union { half8 v; _Float16 e[8]; } bf;
        #pragma unroll
        for (int i = 0; i < 8; ++i) {
          const float* img = xb + (size_t)((2 * ss + laneh) * 8 + i) * HW_;
          float v = g00 * img[yc0 * W_ + xc0] + g01 * img[yc0 * W_ + xc1]
                  + g10 * img[yc1 * W_ + xc0] + g11 * img[yc1 * W_ + xc1];
          bf.e[i] = (_Float16)v;
        }
        const half8 a0 = *(const half8*)&wt2[(ss * 64 + lane) * 8];
        const half8 a1 = *(const half8*)&wt2[((4 + ss) * 64 + lane) * 8];
        acc0 = __builtin_amdgcn_mfma_f32_32x32x16_f16(a0, bf.v, acc0, 0, 0, 0);
        acc1 = __builtin_amdgcn_mfma_f32_32x32x16_f16(a1, bf.v, acc1, 0, 0, 0);
      }
    }
  }

  // ---- epilogue: direct stores (wave owns full M=64 of its strip) ----
  #pragma unroll
  for (int reg = 0; reg < 16; ++reg) {
    const int row = (reg & 3) + 8 * (reg >> 2) + 4 * laneh;
    out[((b * 64 + row)      * H_ + ho) * W_ + px] = acc0[reg] + bias[row];
    out[((b * 64 + 32 + row) * H_ + ho) * W_ + px] = acc1[reg] + bias[32 + row];
  }
}

extern "C" void kernel_launch(void* const* d_in, const int* in_sizes, int n_in,
                              void* d_out, int out_size, void* d_ws, size_t ws_size,
                              hipStream_t stream) {
  const float* x    = (const float*)d_in[0];
  const float* wt   = (const float*)d_in[1];
  const float* bias = (const float*)d_in[2];
  const float* ow   = (const float*)d_in[3];
  const float* ob   = (const float*)d_in[4];
  float* out = (float*)d_out;

  unsigned short* ws_u = (unsigned short*)d_ws;
  unsigned short* w2b  = ws_u;
  unsigned short* w2a  = ws_u + W2B_ELEMS;

  const int pack_blocks = (W2B_ELEMS + W2A_ELEMS + 255) / 256;   // 216
  pack_w_only<<<pack_blocks, 256, 0, stream>>>(wt, ow, ws_u);

  deform_fused13<<<B_ * (H_ / 2), 512, 0, stream>>>(x, bias, ob, w2b, w2a, out);
}